// Round 1
// baseline (273.161 us; speedup 1.0000x reference)
//
#include <hip/hip_runtime.h>
#include <math.h>

typedef __bf16 bf16x8 __attribute__((ext_vector_type(8)));
typedef __bf16 bf16x4 __attribute__((ext_vector_type(4)));
typedef float  f32x4  __attribute__((ext_vector_type(4)));

#define QL    32
#define DL    256
#define DIM   256
#define NK    21
#define KSOFT 20
#define STR   264                 // LDS row stride in bf16 (mono fallback only)
#define L2E   1.4426950408889634f

#if __has_builtin(__builtin_amdgcn_exp2f)
#define EXP2F(x) __builtin_amdgcn_exp2f(x)
#else
#define EXP2F(x) exp2f(x)
#endif

// ---------- Phase 1: stream-normalize the emb table into a bf16 copy in ws ----
// 2 rows per wave for load ILP; 8 rows per 256-thread block.
__global__ __launch_bounds__(256)
void knrm_prep(const float* __restrict__ emb, __bf16* __restrict__ tab, int V)
{
    const int wave = threadIdx.x >> 6;
    const int lane = threadIdx.x & 63;
    const int row0 = (blockIdx.x * 4 + wave) * 2;
    if (row0 >= V) return;                     // V even -> row0+1 also valid

    float4 a = reinterpret_cast<const float4*>(emb + (size_t)row0 * DIM)[lane];
    float4 c = reinterpret_cast<const float4*>(emb + (size_t)(row0 + 1) * DIM)[lane];
    float sa = a.x*a.x + a.y*a.y + a.z*a.z + a.w*a.w;
    float sc = c.x*c.x + c.y*c.y + c.z*c.z + c.w*c.w;
    #pragma unroll
    for (int m = 32; m; m >>= 1) { sa += __shfl_xor(sa, m); sc += __shfl_xor(sc, m); }
    float ia = rsqrtf(fmaxf(sa, 1e-16f));      // ||row|| ~16, ref eps never binds
    float ic = rsqrtf(fmaxf(sc, 1e-16f));
    bf16x4 oa, oc;
    oa[0] = (__bf16)(a.x * ia); oa[1] = (__bf16)(a.y * ia);
    oa[2] = (__bf16)(a.z * ia); oa[3] = (__bf16)(a.w * ia);
    oc[0] = (__bf16)(c.x * ic); oc[1] = (__bf16)(c.y * ic);
    oc[2] = (__bf16)(c.z * ic); oc[3] = (__bf16)(c.w * ic);
    *reinterpret_cast<bf16x4*>(tab + (size_t)row0 * DIM + lane * 4) = oa;
    *reinterpret_cast<bf16x4*>(tab + (size_t)(row0 + 1) * DIM + lane * 4) = oc;
}

// ---------- Phase 2: barrier-free direct-gather MFMA -------------------------
// The bf16 table (51.2 MB) is L3-resident and each tile's 16 doc rows are
// L1/L2-resident across the two q-waves that share them -> LDS staging was
// pure overhead (Common-mistake #7). Fragments are gathered straight into
// VGPRs: q fragments once (loop-invariant), doc fragments per tile into a
// single register buffer whose refill latency hides under the ~1100-cycle
// kernel-eval block. No barriers in the tile loop; LDS only for Sqk/tokens/MLP.
// A = doc / B = query so C col (lane&15) is a FIXED q-row.
__global__ __launch_bounds__(256, 4)   // cap 128 VGPR -> 16 waves/CU resident
void knrm_main6(const int* __restrict__ q1t, const int* __restrict__ d1t,
                const int* __restrict__ q2t, const int* __restrict__ d2t,
                const __bf16* __restrict__ tab,
                const float* __restrict__ W0, const float* __restrict__ b0,
                const float* __restrict__ W1, const float* __restrict__ b1,
                const float* __restrict__ W2, const float* __restrict__ b2,
                float* __restrict__ lg, int B)
{
    const int b    = blockIdx.x;
    const int pair = blockIdx.y;
    const int tid  = threadIdx.x;
    const int wave = tid >> 6;
    const int lane = tid & 63;
    const int qt   = wave >> 1;     // q half (B operand)
    const int dt   = wave & 1;      // doc half (A operand)
    const int g    = lane >> 4;     // k-chunk group == C row group (doc rows)
    const int cl   = lane & 15;     // A row / B row / C col

    const int* qtok = pair ? q2t : q1t;
    const int* dtok = pair ? d2t : d1t;

    __shared__ float Sqk[QL * NK];
    __shared__ int   dtok_s[DL];
    __shared__ int   qtok_s[QL];
    __shared__ float km[NK];
    __shared__ float h0[10];
    __shared__ float h1[5];

    if (tid < QL) qtok_s[tid] = qtok[b * QL + tid];
    dtok_s[tid] = dtok[b * DL + tid];
    for (int e = tid; e < QL * NK; e += 256) Sqk[e] = 0.0f;
    if (tid < NK) km[tid] = 0.0f;
    __syncthreads();

    // ---- this lane's q-row (C column) is fixed for the whole kernel
    const int myq  = qt * 16 + cl;
    const int qtk1 = qtok_s[myq];

    // ---- B fragments: gather once, keep in registers (32 VGPR)
    bf16x8 qreg[8];
    {
        const __bf16* qrow = tab + (size_t)qtk1 * DIM + g * 8;
        #pragma unroll
        for (int ks = 0; ks < 8; ++ks)
            qreg[ks] = *reinterpret_cast<const bf16x8*>(qrow + ks * 32);
    }

    // ---- A fragments, tile 0 (32 VGPR, single buffer — MFMA consumes at
    //      issue, so next tile's loads can safely retarget the same regs)
    bf16x8 areg[8];
    {
        const int tokA = dtok_s[dt * 16 + cl];
        const __bf16* drow = tab + (size_t)tokA * DIM + g * 8;
        #pragma unroll
        for (int ks = 0; ks < 8; ++ks)
            areg[ks] = *reinterpret_cast<const bf16x8*>(drow + ks * 32);
    }

    float acc[NK];
    #pragma unroll
    for (int k = 0; k < NK; ++k) acc[k] = 0.0f;

    for (int tile = 0; tile < 8; ++tile) {
        // ---- 16x16x32 MFMA over K=256 (waits vmcnt for this tile's gathers)
        f32x4 cf = {0.0f, 0.0f, 0.0f, 0.0f};
        #pragma unroll
        for (int ks = 0; ks < 8; ++ks)
            cf = __builtin_amdgcn_mfma_f32_16x16x32_bf16(areg[ks], qreg[ks], cf, 0, 0, 0);

        // ---- issue next tile's gathers; they fly under this tile's eval
        if (tile < 7) {
            const int tokA = dtok_s[(tile + 1) * 32 + dt * 16 + cl];
            const __bf16* drow = tab + (size_t)tokA * DIM + g * 8;
            #pragma unroll
            for (int ks = 0; ks < 8; ++ks)
                areg[ks] = *reinterpret_cast<const bf16x8*>(drow + ks * 32);
        }

        // ---- eval off the fragment: cf[i] = mm[doc=tile*32+dt*16+g*4+i][q=myq]
        #pragma unroll
        for (int i = 0; i < 4; ++i) {
            float mm  = cf[i];
            float mm2 = mm * mm;
            #pragma unroll
            for (int k = 0; k < KSOFT; ++k) {
                float mu = -0.95f + 0.1f * (float)k;          // compile-time
                float a1 = 100.0f * L2E * mu;
                float a0 = -50.0f * L2E * mu * mu;
                float arg = fmaf(a1, mm, fmaf(-50.0f * L2E, mm2, a0));
                acc[k] += EXP2F(arg);
            }
            // exact kernel (sigma=0.001) == 1[token match]
            int drow = tile * 32 + dt * 16 + g * 4 + i;
            acc[KSOFT] += (dtok_s[drow] == qtk1) ? 1.0f : 0.0f;
        }
    }

    // ---- flush: 8 lanes (4 g-groups x 2 dt-waves) merge per q-row
    #pragma unroll
    for (int k = 0; k < NK; ++k)
        atomicAdd(&Sqk[myq * NK + k], acc[k]);
    __syncthreads();

    // ---- km[k] = sum_q log1p(Sqk[q][k])
    for (int e = tid; e < QL * NK; e += 256)
        atomicAdd(&km[e % NK], log1pf(Sqk[e]));
    __syncthreads();

    // ---- tiny MLP 21 -> 10 -> 5 -> 1
    if (tid < 10) {
        float h = b0[tid];
        #pragma unroll
        for (int k = 0; k < NK; ++k) h = fmaf(km[k], W0[tid*NK + k], h);
        h0[tid] = fmaxf(h, 0.0f);
    }
    __syncthreads();
    if (tid < 5) {
        float h = b1[tid];
        #pragma unroll
        for (int j = 0; j < 10; ++j) h = fmaf(h0[j], W1[tid*10 + j], h);
        h1[tid] = fmaxf(h, 0.0f);
    }
    __syncthreads();
    if (tid == 0) {
        float l = b2[0];
        #pragma unroll
        for (int j = 0; j < 5; ++j) l = fmaf(h1[j], W2[j], l);
        lg[pair * B + b] = l;
    }
}

__global__ void knrm_final(const float* __restrict__ lg, float* __restrict__ out, int B)
{
    int i = blockIdx.x * 256 + threadIdx.x;
    if (i < B) {
        float z = lg[i] - lg[B + i];
        out[i] = 1.0f / (1.0f + expf(-z));
    }
}

// ---------- Fallback (monolithic): only if ws can't hold the bf16 table ------
__global__ __launch_bounds__(256, 2)
void knrm_mono(const int* __restrict__ q1t, const int* __restrict__ d1t,
               const int* __restrict__ q2t, const int* __restrict__ d2t,
               const float* __restrict__ emb,
               const float* __restrict__ W0, const float* __restrict__ b0,
               const float* __restrict__ W1, const float* __restrict__ b1,
               const float* __restrict__ W2, const float* __restrict__ b2,
               float* __restrict__ out)
{
    const int b    = blockIdx.x;
    const int tid  = threadIdx.x;
    const int wave = tid >> 6;
    const int lane = tid & 63;
    const int qt   = wave >> 1;
    const int dt   = wave & 1;
    const int g    = lane >> 4;
    const int cl   = lane & 15;

    __shared__ __align__(16) __bf16 qbuf[QL * STR];
    __shared__ __align__(16) __bf16 dbuf[32 * STR];
    __shared__ float Sqk[QL * NK];
    __shared__ int   dtok_s[DL];
    __shared__ int   qtok_s[QL];
    __shared__ float km[NK];
    __shared__ float h0[10];
    __shared__ float h1[5];
    __shared__ float logit[2];

    for (int pair = 0; pair < 2; ++pair) {
        const int* qtok = pair ? q2t : q1t;
        const int* dtok = pair ? d2t : d1t;

        if (tid < QL) qtok_s[tid] = qtok[b * QL + tid];
        dtok_s[tid] = dtok[b * DL + tid];
        for (int e = tid; e < QL * NK; e += 256) Sqk[e] = 0.0f;
        if (tid < NK) km[tid] = 0.0f;
        __syncthreads();

        #pragma unroll
        for (int i = 0; i < 8; ++i) {
            int row = wave * 8 + i;
            int tok = qtok_s[row];
            float4 v = reinterpret_cast<const float4*>(emb + (size_t)tok * DIM)[lane];
            float s = v.x*v.x + v.y*v.y + v.z*v.z + v.w*v.w;
            #pragma unroll
            for (int m = 32; m; m >>= 1) s += __shfl_xor(s, m);
            float inv = rsqrtf(fmaxf(s, 1e-16f));
            bf16x4 o;
            o[0] = (__bf16)(v.x * inv); o[1] = (__bf16)(v.y * inv);
            o[2] = (__bf16)(v.z * inv); o[3] = (__bf16)(v.w * inv);
            *reinterpret_cast<bf16x4*>(&qbuf[row * STR + lane * 4]) = o;
        }

        int qtk[4];
        #pragma unroll
        for (int i = 0; i < 4; ++i) qtk[i] = qtok_s[qt * 16 + g * 4 + i];

        float acc[4 * NK];
        #pragma unroll
        for (int e = 0; e < 4 * NK; ++e) acc[e] = 0.0f;

        for (int tile = 0; tile < 8; ++tile) {
            #pragma unroll
            for (int i = 0; i < 8; ++i) {
                int r = wave * 8 + i;
                int tok = dtok_s[tile * 32 + r];
                float4 v = reinterpret_cast<const float4*>(emb + (size_t)tok * DIM)[lane];
                float s = v.x*v.x + v.y*v.y + v.z*v.z + v.w*v.w;
                #pragma unroll
                for (int m = 32; m; m >>= 1) s += __shfl_xor(s, m);
                float inv = rsqrtf(fmaxf(s, 1e-16f));
                bf16x4 o;
                o[0] = (__bf16)(v.x * inv); o[1] = (__bf16)(v.y * inv);
                o[2] = (__bf16)(v.z * inv); o[3] = (__bf16)(v.w * inv);
                *reinterpret_cast<bf16x4*>(&dbuf[r * STR + lane * 4]) = o;
            }
            __syncthreads();

            f32x4 cf = {0.0f, 0.0f, 0.0f, 0.0f};
            #pragma unroll
            for (int ks = 0; ks < 8; ++ks) {
                bf16x8 af  = *reinterpret_cast<const bf16x8*>(&qbuf[(qt*16 + cl)*STR + ks*32 + g*8]);
                bf16x8 bfr = *reinterpret_cast<const bf16x8*>(&dbuf[(dt*16 + cl)*STR + ks*32 + g*8]);
                cf = __builtin_amdgcn_mfma_f32_16x16x32_bf16(af, bfr, cf, 0, 0, 0);
            }

            int dtk = dtok_s[tile*32 + dt*16 + cl];
            #pragma unroll
            for (int i = 0; i < 4; ++i) {
                float mm  = cf[i];
                float mm2 = mm * mm;
                #pragma unroll
                for (int k = 0; k < KSOFT; ++k) {
                    float mu = -0.95f + 0.1f * (float)k;
                    float a1 = 100.0f * L2E * mu;
                    float a0 = -50.0f * L2E * mu * mu;
                    float arg = fmaf(a1, mm, fmaf(-50.0f * L2E, mm2, a0));
                    acc[i*NK + k] += EXP2F(arg);
                }
                acc[i*NK + KSOFT] += (dtk == qtk[i]) ? 1.0f : 0.0f;
            }
            __syncthreads();
        }

        #pragma unroll
        for (int i = 0; i < 4; ++i) {
            int row = qt*16 + g*4 + i;
            #pragma unroll
            for (int k = 0; k < NK; ++k)
                atomicAdd(&Sqk[row*NK + k], acc[i*NK + k]);
        }
        __syncthreads();

        for (int e = tid; e < QL * NK; e += 256)
            atomicAdd(&km[e % NK], log1pf(Sqk[e]));
        __syncthreads();

        if (tid < 10) {
            float h = b0[tid];
            #pragma unroll
            for (int k = 0; k < NK; ++k) h = fmaf(km[k], W0[tid*NK + k], h);
            h0[tid] = fmaxf(h, 0.0f);
        }
        __syncthreads();
        if (tid < 5) {
            float h = b1[tid];
            #pragma unroll
            for (int j = 0; j < 10; ++j) h = fmaf(h0[j], W1[tid*10 + j], h);
            h1[tid] = fmaxf(h, 0.0f);
        }
        __syncthreads();
        if (tid == 0) {
            float l = b2[0];
            #pragma unroll
            for (int j = 0; j < 5; ++j) l = fmaf(h1[j], W2[j], l);
            logit[pair] = l;
        }
        __syncthreads();
    }

    if (tid == 0) {
        float z = logit[0] - logit[1];
        out[b] = 1.0f / (1.0f + expf(-z));
    }
}

extern "C" void kernel_launch(void* const* d_in, const int* in_sizes, int n_in,
                              void* d_out, int out_size, void* d_ws, size_t ws_size,
                              hipStream_t stream) {
    const int*   q1  = (const int*)d_in[0];
    const int*   d1  = (const int*)d_in[1];
    const int*   q2  = (const int*)d_in[2];
    const int*   d2  = (const int*)d_in[3];
    const float* emb = (const float*)d_in[4];
    const float* W0  = (const float*)d_in[5];
    const float* b0  = (const float*)d_in[6];
    const float* W1  = (const float*)d_in[7];
    const float* b1  = (const float*)d_in[8];
    const float* W2  = (const float*)d_in[9];
    const float* b2  = (const float*)d_in[10];
    float* out = (float*)d_out;

    const int B = in_sizes[0] / QL;       // 512
    const int V = in_sizes[4] / DIM;      // 100000

    size_t tab_bytes = (size_t)V * DIM * sizeof(__bf16);
    size_t need = tab_bytes + 256 + (size_t)2 * B * sizeof(float);

    if (ws_size >= need) {
        __bf16* tab = (__bf16*)d_ws;
        float*  lg  = (float*)((char*)d_ws + ((tab_bytes + 255) & ~(size_t)255));

        knrm_prep<<<(V/2 + 3) / 4, 256, 0, stream>>>(emb, tab, V);
        dim3 grid(B, 2);
        knrm_main6<<<grid, 256, 0, stream>>>(q1, d1, q2, d2, tab,
                                             W0, b0, W1, b1, W2, b2, lg, B);
        knrm_final<<<(B + 255) / 256, 256, 0, stream>>>(lg, out, B);
    } else {
        knrm_mono<<<B, 256, 0, stream>>>(q1, d1, q2, d2, emb,
                                         W0, b0, W1, b1, W2, b2, out);
    }
}

// Round 3
// 267.639 us; speedup vs baseline: 1.0206x; 1.0206x over previous
//
#include <hip/hip_runtime.h>
#include <math.h>

typedef __bf16 bf16x8 __attribute__((ext_vector_type(8)));
typedef __bf16 bf16x4 __attribute__((ext_vector_type(4)));
typedef float  f32x4  __attribute__((ext_vector_type(4)));

#define QL    32
#define DL    256
#define DIM   256
#define NK    21
#define KSOFT 20
#define STR   264                 // LDS row stride in bf16: 528 B, 16-B aligned
#define L2E   1.4426950408889634f

#if __has_builtin(__builtin_amdgcn_exp2f)
#define EXP2F(x) __builtin_amdgcn_exp2f(x)
#else
#define EXP2F(x) exp2f(x)
#endif

// ---------- Phase 1: stream-normalize the emb table into a bf16 copy in ws ----
__global__ __launch_bounds__(256)
void knrm_prep(const float* __restrict__ emb, __bf16* __restrict__ tab, int V)
{
    const int wave = threadIdx.x >> 6;
    const int lane = threadIdx.x & 63;
    const int row0 = (blockIdx.x * 4 + wave) * 2;
    if (row0 >= V) return;                     // V even -> row0+1 also valid

    float4 a = reinterpret_cast<const float4*>(emb + (size_t)row0 * DIM)[lane];
    float4 c = reinterpret_cast<const float4*>(emb + (size_t)(row0 + 1) * DIM)[lane];
    float sa = a.x*a.x + a.y*a.y + a.z*a.z + a.w*a.w;
    float sc = c.x*c.x + c.y*c.y + c.z*c.z + c.w*c.w;
    #pragma unroll
    for (int m = 32; m; m >>= 1) { sa += __shfl_xor(sa, m); sc += __shfl_xor(sc, m); }
    float ia = rsqrtf(fmaxf(sa, 1e-16f));      // ||row|| ~16, ref eps never binds
    float ic = rsqrtf(fmaxf(sc, 1e-16f));
    bf16x4 oa, oc;
    oa[0] = (__bf16)(a.x * ia); oa[1] = (__bf16)(a.y * ia);
    oa[2] = (__bf16)(a.z * ia); oa[3] = (__bf16)(a.w * ia);
    oc[0] = (__bf16)(c.x * ic); oc[1] = (__bf16)(c.y * ic);
    oc[2] = (__bf16)(c.z * ic); oc[3] = (__bf16)(c.w * ic);
    *reinterpret_cast<bf16x4*>(tab + (size_t)row0 * DIM + lane * 4) = oa;
    *reinterpret_cast<bf16x4*>(tab + (size_t)(row0 + 1) * DIM + lane * 4) = oc;
}

// ---------- Phase 2: staged doc tiles (traffic dedup) + q-in-regs +
//            double-buffered LDS with ONE barrier per tile --------------------
// main5 (68us) was serialization-bound: 2 barriers/tile convoy + 16 conflicted
// ds_reads/tile. main6 (112us) proved gathers sustain 2.3 TB/s but tripled HBM
// traffic by dropping the per-block dedup. main7 keeps the dedup (doc rows
// fetched once per block, coalesced, broadcast via LDS) and removes the
// serialization: q fragments in registers (kills 8/16 ds_reads), dbuf double-
// buffered (1 barrier/tile), gathers issued at loop top and committed after
// eval (~1100 cyc cover). A = doc / B = query so C col (lane&15) = fixed q-row.
__global__ __launch_bounds__(256, 4)
void knrm_main7(const int* __restrict__ q1t, const int* __restrict__ d1t,
                const int* __restrict__ q2t, const int* __restrict__ d2t,
                const __bf16* __restrict__ tab,
                const float* __restrict__ W0, const float* __restrict__ b0,
                const float* __restrict__ W1, const float* __restrict__ b1,
                const float* __restrict__ W2, const float* __restrict__ b2,
                float* __restrict__ lg, int B)
{
    const int b    = blockIdx.x;
    const int pair = blockIdx.y;
    const int tid  = threadIdx.x;
    const int wave = tid >> 6;
    const int lane = tid & 63;
    const int qt   = wave >> 1;     // q half (B operand)
    const int dt   = wave & 1;      // doc half (A operand)
    const int g    = lane >> 4;     // k-chunk group == C row group (doc rows)
    const int cl   = lane & 15;     // A row / B row / C col
    const int hl   = lane & 31;     // half-wave lane
    const int hw   = lane >> 5;     // which half-wave

    const int* qtok = pair ? q2t : q1t;
    const int* dtok = pair ? d2t : d1t;

    __shared__ __align__(16) __bf16 dbuf[2][32 * STR];   // 33.8 KB
    __shared__ float Sqk[QL * NK];
    __shared__ int   dtok_s[DL];
    __shared__ int   qtok_s[QL];
    __shared__ float km[NK];
    __shared__ float h0[10];
    __shared__ float h1[5];

    if (tid < QL) qtok_s[tid] = qtok[b * QL + tid];
    dtok_s[tid] = dtok[b * DL + tid];
    for (int e = tid; e < QL * NK; e += 256) Sqk[e] = 0.0f;
    if (tid < NK) km[tid] = 0.0f;
    __syncthreads();

    // ---- this lane's q-row (C column) is fixed for the whole kernel
    const int myq  = qt * 16 + cl;
    const int qtk1 = qtok_s[myq];

    // ---- B fragments: gather once, keep in registers (32 VGPR)
    bf16x8 qreg[8];
    {
        const __bf16* qrow = tab + (size_t)qtk1 * DIM + g * 8;
        #pragma unroll
        for (int ks = 0; ks < 8; ++ks)
            qreg[ks] = *reinterpret_cast<const bf16x8*>(qrow + ks * 32);
    }

    // ---- stage doc tile 0: wave-cooperative, coalesced (2 rows per load)
    bf16x8 dreg[4];
    #pragma unroll
    for (int i = 0; i < 4; ++i) {
        int r = wave * 8 + i * 2 + hw;
        dreg[i] = *reinterpret_cast<const bf16x8*>(
            tab + (size_t)dtok_s[r] * DIM + hl * 8);
    }
    #pragma unroll
    for (int i = 0; i < 4; ++i) {
        int r = wave * 8 + i * 2 + hw;
        *reinterpret_cast<bf16x8*>(&dbuf[0][r * STR + hl * 8]) = dreg[i];
    }
    __syncthreads();           // dbuf[0] visible

    float acc[NK];
    #pragma unroll
    for (int k = 0; k < NK; ++k) acc[k] = 0.0f;

    for (int tile = 0; tile < 8; ++tile) {
        const int cur = tile & 1;

        // ---- issue next tile's gathers; commit after eval (max flight time)
        if (tile < 7) {
            #pragma unroll
            for (int i = 0; i < 4; ++i) {
                int r = wave * 8 + i * 2 + hw;
                dreg[i] = *reinterpret_cast<const bf16x8*>(
                    tab + (size_t)dtok_s[(tile + 1) * 32 + r] * DIM + hl * 8);
            }
        }

        // ---- 16x16x32 MFMA over K=256; A = doc rows (LDS), B = q rows (regs)
        f32x4 cf = {0.0f, 0.0f, 0.0f, 0.0f};
        #pragma unroll
        for (int ks = 0; ks < 8; ++ks) {
            bf16x8 dfr = *reinterpret_cast<const bf16x8*>(
                &dbuf[cur][(dt*16 + cl)*STR + ks*32 + g*8]);
            cf = __builtin_amdgcn_mfma_f32_16x16x32_bf16(dfr, qreg[ks], cf, 0, 0, 0);
        }

        // ---- eval off the fragment: cf[i] = mm[doc=tile*32+dt*16+g*4+i][q=myq]
        #pragma unroll
        for (int i = 0; i < 4; ++i) {
            float mm  = cf[i];
            float mm2 = mm * mm;
            #pragma unroll
            for (int k = 0; k < KSOFT; ++k) {
                float mu = -0.95f + 0.1f * (float)k;          // compile-time
                float a1 = 100.0f * L2E * mu;
                float a0 = -50.0f * L2E * mu * mu;
                float arg = fmaf(a1, mm, fmaf(-50.0f * L2E, mm2, a0));
                acc[k] += EXP2F(arg);
            }
            // exact kernel (sigma=0.001) == 1[token match]
            int drow = tile * 32 + dt * 16 + g * 4 + i;
            acc[KSOFT] += (dtok_s[drow] == qtk1) ? 1.0f : 0.0f;
        }

        // ---- commit prefetched rows to the other buffer; ONE barrier/tile.
        // dbuf[cur^1]'s last readers finished before the barrier that opened
        // THIS tile, so writing it here is race-free; the barrier below both
        // publishes these writes and retires this tile's dbuf[cur] reads.
        if (tile < 7) {
            #pragma unroll
            for (int i = 0; i < 4; ++i) {
                int r = wave * 8 + i * 2 + hw;
                *reinterpret_cast<bf16x8*>(&dbuf[cur ^ 1][r * STR + hl * 8]) = dreg[i];
            }
            __syncthreads();
        }
    }

    // ---- flush: 8 lanes (4 g-groups x 2 dt-waves) merge per q-row
    #pragma unroll
    for (int k = 0; k < NK; ++k)
        atomicAdd(&Sqk[myq * NK + k], acc[k]);
    __syncthreads();

    // ---- km[k] = sum_q log1p(Sqk[q][k])
    for (int e = tid; e < QL * NK; e += 256)
        atomicAdd(&km[e % NK], log1pf(Sqk[e]));
    __syncthreads();

    // ---- tiny MLP 21 -> 10 -> 5 -> 1
    if (tid < 10) {
        float h = b0[tid];
        #pragma unroll
        for (int k = 0; k < NK; ++k) h = fmaf(km[k], W0[tid*NK + k], h);
        h0[tid] = fmaxf(h, 0.0f);
    }
    __syncthreads();
    if (tid < 5) {
        float h = b1[tid];
        #pragma unroll
        for (int j = 0; j < 10; ++j) h = fmaf(h0[j], W1[tid*10 + j], h);
        h1[tid] = fmaxf(h, 0.0f);
    }
    __syncthreads();
    if (tid == 0) {
        float l = b2[0];
        #pragma unroll
        for (int j = 0; j < 5; ++j) l = fmaf(h1[j], W2[j], l);
        lg[pair * B + b] = l;
    }
}

__global__ void knrm_final(const float* __restrict__ lg, float* __restrict__ out, int B)
{
    int i = blockIdx.x * 256 + threadIdx.x;
    if (i < B) {
        float z = lg[i] - lg[B + i];
        out[i] = 1.0f / (1.0f + expf(-z));
    }
}

// ---------- Fallback (monolithic): only if ws can't hold the bf16 table ------
__global__ __launch_bounds__(256, 2)
void knrm_mono(const int* __restrict__ q1t, const int* __restrict__ d1t,
               const int* __restrict__ q2t, const int* __restrict__ d2t,
               const float* __restrict__ emb,
               const float* __restrict__ W0, const float* __restrict__ b0,
               const float* __restrict__ W1, const float* __restrict__ b1,
               const float* __restrict__ W2, const float* __restrict__ b2,
               float* __restrict__ out)
{
    const int b    = blockIdx.x;
    const int tid  = threadIdx.x;
    const int wave = tid >> 6;
    const int lane = tid & 63;
    const int qt   = wave >> 1;
    const int dt   = wave & 1;
    const int g    = lane >> 4;
    const int cl   = lane & 15;

    __shared__ __align__(16) __bf16 qbuf[QL * STR];
    __shared__ __align__(16) __bf16 dbuf[32 * STR];
    __shared__ float Sqk[QL * NK];
    __shared__ int   dtok_s[DL];
    __shared__ int   qtok_s[QL];
    __shared__ float km[NK];
    __shared__ float h0[10];
    __shared__ float h1[5];
    __shared__ float logit[2];

    for (int pair = 0; pair < 2; ++pair) {
        const int* qtok = pair ? q2t : q1t;
        const int* dtok = pair ? d2t : d1t;

        if (tid < QL) qtok_s[tid] = qtok[b * QL + tid];
        dtok_s[tid] = dtok[b * DL + tid];
        for (int e = tid; e < QL * NK; e += 256) Sqk[e] = 0.0f;
        if (tid < NK) km[tid] = 0.0f;
        __syncthreads();

        #pragma unroll
        for (int i = 0; i < 8; ++i) {
            int row = wave * 8 + i;
            int tok = qtok_s[row];
            float4 v = reinterpret_cast<const float4*>(emb + (size_t)tok * DIM)[lane];
            float s = v.x*v.x + v.y*v.y + v.z*v.z + v.w*v.w;
            #pragma unroll
            for (int m = 32; m; m >>= 1) s += __shfl_xor(s, m);
            float inv = rsqrtf(fmaxf(s, 1e-16f));
            bf16x4 o;
            o[0] = (__bf16)(v.x * inv); o[1] = (__bf16)(v.y * inv);
            o[2] = (__bf16)(v.z * inv); o[3] = (__bf16)(v.w * inv);
            *reinterpret_cast<bf16x4*>(&qbuf[row * STR + lane * 4]) = o;
        }

        int qtk[4];
        #pragma unroll
        for (int i = 0; i < 4; ++i) qtk[i] = qtok_s[qt * 16 + g * 4 + i];

        float acc[4 * NK];
        #pragma unroll
        for (int e = 0; e < 4 * NK; ++e) acc[e] = 0.0f;

        for (int tile = 0; tile < 8; ++tile) {
            #pragma unroll
            for (int i = 0; i < 8; ++i) {
                int r = wave * 8 + i;
                int tok = dtok_s[tile * 32 + r];
                float4 v = reinterpret_cast<const float4*>(emb + (size_t)tok * DIM)[lane];
                float s = v.x*v.x + v.y*v.y + v.z*v.z + v.w*v.w;
                #pragma unroll
                for (int m = 32; m; m >>= 1) s += __shfl_xor(s, m);
                float inv = rsqrtf(fmaxf(s, 1e-16f));
                bf16x4 o;
                o[0] = (__bf16)(v.x * inv); o[1] = (__bf16)(v.y * inv);
                o[2] = (__bf16)(v.z * inv); o[3] = (__bf16)(v.w * inv);
                *reinterpret_cast<bf16x4*>(&dbuf[r * STR + lane * 4]) = o;
            }
            __syncthreads();

            f32x4 cf = {0.0f, 0.0f, 0.0f, 0.0f};
            #pragma unroll
            for (int ks = 0; ks < 8; ++ks) {
                bf16x8 af  = *reinterpret_cast<const bf16x8*>(&qbuf[(qt*16 + cl)*STR + ks*32 + g*8]);
                bf16x8 bfr = *reinterpret_cast<const bf16x8*>(&dbuf[(dt*16 + cl)*STR + ks*32 + g*8]);
                cf = __builtin_amdgcn_mfma_f32_16x16x32_bf16(af, bfr, cf, 0, 0, 0);
            }

            int dtk = dtok_s[tile*32 + dt*16 + cl];
            #pragma unroll
            for (int i = 0; i < 4; ++i) {
                float mm  = cf[i];
                float mm2 = mm * mm;
                #pragma unroll
                for (int k = 0; k < KSOFT; ++k) {
                    float mu = -0.95f + 0.1f * (float)k;
                    float a1 = 100.0f * L2E * mu;
                    float a0 = -50.0f * L2E * mu * mu;
                    float arg = fmaf(a1, mm, fmaf(-50.0f * L2E, mm2, a0));
                    acc[i*NK + k] += EXP2F(arg);
                }
                acc[i*NK + KSOFT] += (dtk == qtk[i]) ? 1.0f : 0.0f;
            }
            __syncthreads();
        }

        #pragma unroll
        for (int i = 0; i < 4; ++i) {
            int row = qt*16 + g*4 + i;
            #pragma unroll
            for (int k = 0; k < NK; ++k)
                atomicAdd(&Sqk[row*NK + k], acc[i*NK + k]);
        }
        __syncthreads();

        for (int e = tid; e < QL * NK; e += 256)
            atomicAdd(&km[e % NK], log1pf(Sqk[e]));
        __syncthreads();

        if (tid < 10) {
            float h = b0[tid];
            #pragma unroll
            for (int k = 0; k < NK; ++k) h = fmaf(km[k], W0[tid*NK + k], h);
            h0[tid] = fmaxf(h, 0.0f);
        }
        __syncthreads();
        if (tid < 5) {
            float h = b1[tid];
            #pragma unroll
            for (int j = 0; j < 10; ++j) h = fmaf(h0[j], W1[tid*10 + j], h);
            h1[tid] = fmaxf(h, 0.0f);
        }
        __syncthreads();
        if (tid == 0) {
            float l = b2[0];
            #pragma unroll
            for (int j = 0; j < 5; ++j) l = fmaf(h1[j], W2[j], l);
            logit[pair] = l;
        }
        __syncthreads();
    }

    if (tid == 0) {
        float z = logit[0] - logit[1];
        out[b] = 1.0f / (1.0f + expf(-z));
    }
}

extern "C" void kernel_launch(void* const* d_in, const int* in_sizes, int n_in,
                              void* d_out, int out_size, void* d_ws, size_t ws_size,
                              hipStream_t stream) {
    const int*   q1  = (const int*)d_in[0];
    const int*   d1  = (const int*)d_in[1];
    const int*   q2  = (const int*)d_in[2];
    const int*   d2  = (const int*)d_in[3];
    const float* emb = (const float*)d_in[4];
    const float* W0  = (const float*)d_in[5];
    const float* b0  = (const float*)d_in[6];
    const float* W1  = (const float*)d_in[7];
    const float* b1  = (const float*)d_in[8];
    const float* W2  = (const float*)d_in[9];
    const float* b2  = (const float*)d_in[10];
    float* out = (float*)d_out;

    const int B = in_sizes[0] / QL;       // 512
    const int V = in_sizes[4] / DIM;      // 100000

    size_t tab_bytes = (size_t)V * DIM * sizeof(__bf16);
    size_t need = tab_bytes + 256 + (size_t)2 * B * sizeof(float);

    if (ws_size >= need) {
        __bf16* tab = (__bf16*)d_ws;
        float*  lg  = (float*)((char*)d_ws + ((tab_bytes + 255) & ~(size_t)255));

        knrm_prep<<<(V/2 + 3) / 4, 256, 0, stream>>>(emb, tab, V);
        dim3 grid(B, 2);
        knrm_main7<<<grid, 256, 0, stream>>>(q1, d1, q2, d2, tab,
                                             W0, b0, W1, b1, W2, b2, lg, B);
        knrm_final<<<(B + 255) / 256, 256, 0, stream>>>(lg, out, B);
    } else {
        knrm_mono<<<B, 256, 0, stream>>>(q1, d1, q2, d2, emb,
                                         W0, b0, W1, b1, W2, b2, out);
    }
}

// Round 4
// 235.918 us; speedup vs baseline: 1.1579x; 1.1345x over previous
//
#include <hip/hip_runtime.h>
#include <math.h>

typedef __bf16 bf16x8 __attribute__((ext_vector_type(8)));
typedef __bf16 bf16x4 __attribute__((ext_vector_type(4)));
typedef float  f32x4  __attribute__((ext_vector_type(4)));

#define QL    32
#define DL    256
#define DIM   256
#define NK    21
#define KSOFT 20
#define STR   264                 // LDS row stride in bf16: 528 B, 16-B aligned
#define L2E   1.4426950408889634f

#if __has_builtin(__builtin_amdgcn_exp2f)
#define EXP2F(x) __builtin_amdgcn_exp2f(x)
#else
#define EXP2F(x) exp2f(x)
#endif

// Gaussian soft bins, anchored geometric recurrence:
//   E_k = exp(-50 (mm - mu_k)^2), mu_k = -0.95 + 0.1k
//   E_{k+1} = E_k * U * e^{-k},   U = e^{10 mm + 9}
// Anchors at k = 0, 7, 14 (spans <= 6 steps). Underflowed anchors only zero
// terms whose true value < 1e-38 -> negligible in Sqk sums.
// 4 transcendentals/element instead of 20.
#define EVAL_BINS(mm, ACC0)                                                  \
    {                                                                        \
        float U  = EXP2F(L2E * fmaf(10.0f, (mm), 9.0f));                     \
        float t0 = (mm) + 0.95f;                                             \
        float E  = EXP2F((-50.0f * L2E) * t0 * t0);                          \
        ACC0[0] += E;                                                        \
        E *= U;                           ACC0[1]  += E; /* e^-0  */         \
        E *= U * 0.36787944117144233f;    ACC0[2]  += E; /* e^-1  */         \
        E *= U * 0.1353352832366127f;     ACC0[3]  += E; /* e^-2  */         \
        E *= U * 0.049787068367863944f;   ACC0[4]  += E; /* e^-3  */         \
        E *= U * 0.018315638888734179f;   ACC0[5]  += E; /* e^-4  */         \
        E *= U * 0.006737946999085467f;   ACC0[6]  += E; /* e^-5  */         \
        float t7 = (mm) + 0.25f;                                             \
        E = EXP2F((-50.0f * L2E) * t7 * t7);                                 \
        ACC0[7] += E;                                                        \
        E *= U * 0.0009118819655545162f;  ACC0[8]  += E; /* e^-7  */         \
        E *= U * 0.00033546262790251185f; ACC0[9]  += E; /* e^-8  */         \
        E *= U * 0.0001234098040866796f;  ACC0[10] += E; /* e^-9  */         \
        E *= U * 4.5399929762484854e-05f; ACC0[11] += E; /* e^-10 */         \
        E *= U * 1.670170079024566e-05f;  ACC0[12] += E; /* e^-11 */         \
        E *= U * 6.14421235332821e-06f;   ACC0[13] += E; /* e^-12 */         \
        float t14 = (mm) - 0.45f;                                            \
        E = EXP2F((-50.0f * L2E) * t14 * t14);                               \
        ACC0[14] += E;                                                       \
        E *= U * 8.315287191035679e-07f;  ACC0[15] += E; /* e^-14 */         \
        E *= U * 3.059023205018258e-07f;  ACC0[16] += E; /* e^-15 */         \
        E *= U * 1.1253517471925912e-07f; ACC0[17] += E; /* e^-16 */         \
        E *= U * 4.139937718785167e-08f;  ACC0[18] += E; /* e^-17 */         \
        E *= U * 1.522997974471263e-08f;  ACC0[19] += E; /* e^-18 */         \
    }

// ---------- Phase 1: stream-normalize the emb table into a bf16 copy in ws ----
__global__ __launch_bounds__(256)
void knrm_prep(const float* __restrict__ emb, __bf16* __restrict__ tab, int V)
{
    const int wave = threadIdx.x >> 6;
    const int lane = threadIdx.x & 63;
    const int row0 = (blockIdx.x * 4 + wave) * 2;
    if (row0 >= V) return;                     // V even -> row0+1 also valid

    float4 a = reinterpret_cast<const float4*>(emb + (size_t)row0 * DIM)[lane];
    float4 c = reinterpret_cast<const float4*>(emb + (size_t)(row0 + 1) * DIM)[lane];
    float sa = a.x*a.x + a.y*a.y + a.z*a.z + a.w*a.w;
    float sc = c.x*c.x + c.y*c.y + c.z*c.z + c.w*c.w;
    #pragma unroll
    for (int m = 32; m; m >>= 1) { sa += __shfl_xor(sa, m); sc += __shfl_xor(sc, m); }
    float ia = rsqrtf(fmaxf(sa, 1e-16f));      // ||row|| ~16, ref eps never binds
    float ic = rsqrtf(fmaxf(sc, 1e-16f));
    bf16x4 oa, oc;
    oa[0] = (__bf16)(a.x * ia); oa[1] = (__bf16)(a.y * ia);
    oa[2] = (__bf16)(a.z * ia); oa[3] = (__bf16)(a.w * ia);
    oc[0] = (__bf16)(c.x * ic); oc[1] = (__bf16)(c.y * ic);
    oc[2] = (__bf16)(c.z * ic); oc[3] = (__bf16)(c.w * ic);
    *reinterpret_cast<bf16x4*>(tab + (size_t)row0 * DIM + lane * 4) = oa;
    *reinterpret_cast<bf16x4*>(tab + (size_t)(row0 + 1) * DIM + lane * 4) = oc;
}

// ---------- Phase 2: main5 structure (proven 69 MB fetch, no spill) +
//            recurrence eval (4 exps/elem instead of 20) ----------------------
// Lesson from main6/main7: q-in-registers (+32 VGPR) pushed the kernel over
// the allocation -> 39 MB scratch writes + ~130 MB scratch re-read fetch.
// q stays in LDS; dreg[4]+acc[21] is the proven-fitting register budget.
__global__ __launch_bounds__(256, 4)
void knrm_main8(const int* __restrict__ q1t, const int* __restrict__ d1t,
                const int* __restrict__ q2t, const int* __restrict__ d2t,
                const __bf16* __restrict__ tab,
                const float* __restrict__ W0, const float* __restrict__ b0,
                const float* __restrict__ W1, const float* __restrict__ b1,
                const float* __restrict__ W2, const float* __restrict__ b2,
                float* __restrict__ lg, int B)
{
    const int b    = blockIdx.x;
    const int pair = blockIdx.y;
    const int tid  = threadIdx.x;
    const int wave = tid >> 6;
    const int lane = tid & 63;
    const int qt   = wave >> 1;     // q half (B operand)
    const int dt   = wave & 1;      // doc half (A operand)
    const int g    = lane >> 4;     // k-chunk group == C row group (doc rows)
    const int cl   = lane & 15;     // A row / B row / C col
    const int hl   = lane & 31;     // half-wave lane
    const int hw   = lane >> 5;     // which half-wave

    const int* qtok = pair ? q2t : q1t;
    const int* dtok = pair ? d2t : d1t;

    __shared__ __align__(16) __bf16 qbuf[QL * STR];
    __shared__ __align__(16) __bf16 dbuf[32 * STR];
    __shared__ float Sqk[QL * NK];
    __shared__ int   dtok_s[DL];
    __shared__ int   qtok_s[QL];
    __shared__ float km[NK];
    __shared__ float h0[10];
    __shared__ float h1[5];

    if (tid < QL) qtok_s[tid] = qtok[b * QL + tid];
    dtok_s[tid] = dtok[b * DL + tid];
    for (int e = tid; e < QL * NK; e += 256) Sqk[e] = 0.0f;
    if (tid < NK) km[tid] = 0.0f;
    __syncthreads();

    // ---- stage 8 query rows per wave (pre-normalized bf16; 2 rows per load)
    {
        bf16x8 qv[4];
        #pragma unroll
        for (int i = 0; i < 4; ++i) {
            int r = wave * 8 + i * 2 + hw;
            qv[i] = *reinterpret_cast<const bf16x8*>(
                tab + (size_t)qtok_s[r] * DIM + hl * 8);
        }
        #pragma unroll
        for (int i = 0; i < 4; ++i) {
            int r = wave * 8 + i * 2 + hw;
            *reinterpret_cast<bf16x8*>(&qbuf[r * STR + hl * 8]) = qv[i];
        }
    }

    // ---- prefetch doc tile 0 into registers
    bf16x8 dreg[4];
    #pragma unroll
    for (int i = 0; i < 4; ++i) {
        int r = wave * 8 + i * 2 + hw;
        dreg[i] = *reinterpret_cast<const bf16x8*>(
            tab + (size_t)dtok_s[r] * DIM + hl * 8);
    }

    // ---- this lane's q-row (C column) is fixed for the whole kernel
    const int myq  = qt * 16 + cl;
    const int qtk1 = qtok_s[myq];

    float acc[NK];
    #pragma unroll
    for (int k = 0; k < NK; ++k) acc[k] = 0.0f;

    for (int tile = 0; tile < 8; ++tile) {
        __syncthreads();   // prev tile's dbuf reads done; qbuf ready @tile=0

        // ---- commit prefetched rows to LDS
        #pragma unroll
        for (int i = 0; i < 4; ++i) {
            int r = wave * 8 + i * 2 + hw;
            *reinterpret_cast<bf16x8*>(&dbuf[r * STR + hl * 8]) = dreg[i];
        }
        // ---- issue next tile's gathers; they fly during this tile's compute
        if (tile < 7) {
            #pragma unroll
            for (int i = 0; i < 4; ++i) {
                int r = wave * 8 + i * 2 + hw;
                dreg[i] = *reinterpret_cast<const bf16x8*>(
                    tab + (size_t)dtok_s[(tile + 1) * 32 + r] * DIM + hl * 8);
            }
        }
        __syncthreads();   // dbuf(tile) visible

        // ---- 16x16x32 MFMA over K=256, A = doc rows, B = query rows
        f32x4 cf = {0.0f, 0.0f, 0.0f, 0.0f};
        #pragma unroll
        for (int ks = 0; ks < 8; ++ks) {
            bf16x8 dfr = *reinterpret_cast<const bf16x8*>(&dbuf[(dt*16 + cl)*STR + ks*32 + g*8]);
            bf16x8 qfr = *reinterpret_cast<const bf16x8*>(&qbuf[(qt*16 + cl)*STR + ks*32 + g*8]);
            cf = __builtin_amdgcn_mfma_f32_16x16x32_bf16(dfr, qfr, cf, 0, 0, 0);
        }

        // ---- eval off the fragment: cf[i] = mm[doc=tile*32+dt*16+g*4+i][q=myq]
        #pragma unroll
        for (int i = 0; i < 4; ++i) {
            float mm = cf[i];
            EVAL_BINS(mm, acc);
            // exact kernel (sigma=0.001) == 1[token match]
            int drow = tile*32 + dt*16 + g*4 + i;
            acc[KSOFT] += (dtok_s[drow] == qtk1) ? 1.0f : 0.0f;
        }
    }

    // ---- flush: 8 lanes (4 g-groups x 2 dt-waves) merge per q-row
    #pragma unroll
    for (int k = 0; k < NK; ++k)
        atomicAdd(&Sqk[myq * NK + k], acc[k]);
    __syncthreads();

    // ---- km[k] = sum_q log1p(Sqk[q][k])
    for (int e = tid; e < QL * NK; e += 256)
        atomicAdd(&km[e % NK], log1pf(Sqk[e]));
    __syncthreads();

    // ---- tiny MLP 21 -> 10 -> 5 -> 1
    if (tid < 10) {
        float h = b0[tid];
        #pragma unroll
        for (int k = 0; k < NK; ++k) h = fmaf(km[k], W0[tid*NK + k], h);
        h0[tid] = fmaxf(h, 0.0f);
    }
    __syncthreads();
    if (tid < 5) {
        float h = b1[tid];
        #pragma unroll
        for (int j = 0; j < 10; ++j) h = fmaf(h0[j], W1[tid*10 + j], h);
        h1[tid] = fmaxf(h, 0.0f);
    }
    __syncthreads();
    if (tid == 0) {
        float l = b2[0];
        #pragma unroll
        for (int j = 0; j < 5; ++j) l = fmaf(h1[j], W2[j], l);
        lg[pair * B + b] = l;
    }
}

__global__ void knrm_final(const float* __restrict__ lg, float* __restrict__ out, int B)
{
    int i = blockIdx.x * 256 + threadIdx.x;
    if (i < B) {
        float z = lg[i] - lg[B + i];
        out[i] = 1.0f / (1.0f + expf(-z));
    }
}

// ---------- Fallback (monolithic): only if ws can't hold the bf16 table ------
__global__ __launch_bounds__(256, 2)
void knrm_mono(const int* __restrict__ q1t, const int* __restrict__ d1t,
               const int* __restrict__ q2t, const int* __restrict__ d2t,
               const float* __restrict__ emb,
               const float* __restrict__ W0, const float* __restrict__ b0,
               const float* __restrict__ W1, const float* __restrict__ b1,
               const float* __restrict__ W2, const float* __restrict__ b2,
               float* __restrict__ out)
{
    const int b    = blockIdx.x;
    const int tid  = threadIdx.x;
    const int wave = tid >> 6;
    const int lane = tid & 63;
    const int qt   = wave >> 1;
    const int dt   = wave & 1;
    const int g    = lane >> 4;
    const int cl   = lane & 15;

    __shared__ __align__(16) __bf16 qbuf[QL * STR];
    __shared__ __align__(16) __bf16 dbuf[32 * STR];
    __shared__ float Sqk[QL * NK];
    __shared__ int   dtok_s[DL];
    __shared__ int   qtok_s[QL];
    __shared__ float km[NK];
    __shared__ float h0[10];
    __shared__ float h1[5];
    __shared__ float logit[2];

    for (int pair = 0; pair < 2; ++pair) {
        const int* qtok = pair ? q2t : q1t;
        const int* dtok = pair ? d2t : d1t;

        if (tid < QL) qtok_s[tid] = qtok[b * QL + tid];
        dtok_s[tid] = dtok[b * DL + tid];
        for (int e = tid; e < QL * NK; e += 256) Sqk[e] = 0.0f;
        if (tid < NK) km[tid] = 0.0f;
        __syncthreads();

        #pragma unroll
        for (int i = 0; i < 8; ++i) {
            int row = wave * 8 + i;
            int tok = qtok_s[row];
            float4 v = reinterpret_cast<const float4*>(emb + (size_t)tok * DIM)[lane];
            float s = v.x*v.x + v.y*v.y + v.z*v.z + v.w*v.w;
            #pragma unroll
            for (int m = 32; m; m >>= 1) s += __shfl_xor(s, m);
            float inv = rsqrtf(fmaxf(s, 1e-16f));
            bf16x4 o;
            o[0] = (__bf16)(v.x * inv); o[1] = (__bf16)(v.y * inv);
            o[2] = (__bf16)(v.z * inv); o[3] = (__bf16)(v.w * inv);
            *reinterpret_cast<bf16x4*>(&qbuf[row * STR + lane * 4]) = o;
        }

        int qtk[4];
        #pragma unroll
        for (int i = 0; i < 4; ++i) qtk[i] = qtok_s[qt * 16 + g * 4 + i];

        float acc[4 * NK];
        #pragma unroll
        for (int e = 0; e < 4 * NK; ++e) acc[e] = 0.0f;

        for (int tile = 0; tile < 8; ++tile) {
            #pragma unroll
            for (int i = 0; i < 8; ++i) {
                int r = wave * 8 + i;
                int tok = dtok_s[tile * 32 + r];
                float4 v = reinterpret_cast<const float4*>(emb + (size_t)tok * DIM)[lane];
                float s = v.x*v.x + v.y*v.y + v.z*v.z + v.w*v.w;
                #pragma unroll
                for (int m = 32; m; m >>= 1) s += __shfl_xor(s, m);
                float inv = rsqrtf(fmaxf(s, 1e-16f));
                bf16x4 o;
                o[0] = (__bf16)(v.x * inv); o[1] = (__bf16)(v.y * inv);
                o[2] = (__bf16)(v.z * inv); o[3] = (__bf16)(v.w * inv);
                *reinterpret_cast<bf16x4*>(&dbuf[r * STR + lane * 4]) = o;
            }
            __syncthreads();

            f32x4 cf = {0.0f, 0.0f, 0.0f, 0.0f};
            #pragma unroll
            for (int ks = 0; ks < 8; ++ks) {
                bf16x8 af  = *reinterpret_cast<const bf16x8*>(&qbuf[(qt*16 + cl)*STR + ks*32 + g*8]);
                bf16x8 bfr = *reinterpret_cast<const bf16x8*>(&dbuf[(dt*16 + cl)*STR + ks*32 + g*8]);
                cf = __builtin_amdgcn_mfma_f32_16x16x32_bf16(af, bfr, cf, 0, 0, 0);
            }

            int dtk = dtok_s[tile*32 + dt*16 + cl];
            #pragma unroll
            for (int i = 0; i < 4; ++i) {
                float mm = cf[i];
                float* a4 = &acc[i*NK];
                EVAL_BINS(mm, a4);
                a4[KSOFT] += (dtk == qtk[i]) ? 1.0f : 0.0f;
            }
            __syncthreads();
        }

        #pragma unroll
        for (int i = 0; i < 4; ++i) {
            int row = qt*16 + g*4 + i;
            #pragma unroll
            for (int k = 0; k < NK; ++k)
                atomicAdd(&Sqk[row*NK + k], acc[i*NK + k]);
        }
        __syncthreads();

        for (int e = tid; e < QL * NK; e += 256)
            atomicAdd(&km[e % NK], log1pf(Sqk[e]));
        __syncthreads();

        if (tid < 10) {
            float h = b0[tid];
            #pragma unroll
            for (int k = 0; k < NK; ++k) h = fmaf(km[k], W0[tid*NK + k], h);
            h0[tid] = fmaxf(h, 0.0f);
        }
        __syncthreads();
        if (tid < 5) {
            float h = b1[tid];
            #pragma unroll
            for (int j = 0; j < 10; ++j) h = fmaf(h0[j], W1[tid*10 + j], h);
            h1[tid] = fmaxf(h, 0.0f);
        }
        __syncthreads();
        if (tid == 0) {
            float l = b2[0];
            #pragma unroll
            for (int j = 0; j < 5; ++j) l = fmaf(h1[j], W2[j], l);
            logit[pair] = l;
        }
        __syncthreads();
    }

    if (tid == 0) {
        float z = logit[0] - logit[1];
        out[b] = 1.0f / (1.0f + expf(-z));
    }
}

extern "C" void kernel_launch(void* const* d_in, const int* in_sizes, int n_in,
                              void* d_out, int out_size, void* d_ws, size_t ws_size,
                              hipStream_t stream) {
    const int*   q1  = (const int*)d_in[0];
    const int*   d1  = (const int*)d_in[1];
    const int*   q2  = (const int*)d_in[2];
    const int*   d2  = (const int*)d_in[3];
    const float* emb = (const float*)d_in[4];
    const float* W0  = (const float*)d_in[5];
    const float* b0  = (const float*)d_in[6];
    const float* W1  = (const float*)d_in[7];
    const float* b1  = (const float*)d_in[8];
    const float* W2  = (const float*)d_in[9];
    const float* b2  = (const float*)d_in[10];
    float* out = (float*)d_out;

    const int B = in_sizes[0] / QL;       // 512
    const int V = in_sizes[4] / DIM;      // 100000

    size_t tab_bytes = (size_t)V * DIM * sizeof(__bf16);
    size_t need = tab_bytes + 256 + (size_t)2 * B * sizeof(float);

    if (ws_size >= need) {
        __bf16* tab = (__bf16*)d_ws;
        float*  lg  = (float*)((char*)d_ws + ((tab_bytes + 255) & ~(size_t)255));

        knrm_prep<<<(V/2 + 3) / 4, 256, 0, stream>>>(emb, tab, V);
        dim3 grid(B, 2);
        knrm_main8<<<grid, 256, 0, stream>>>(q1, d1, q2, d2, tab,
                                             W0, b0, W1, b1, W2, b2, lg, B);
        knrm_final<<<(B + 255) / 256, 256, 0, stream>>>(lg, out, B);
    } else {
        knrm_mono<<<B, 256, 0, stream>>>(q1, d1, q2, d2, emb,
                                         W0, b0, W1, b1, W2, b2, out);
    }
}